// Round 4
// baseline (267.248 us; speedup 1.0000x reference)
//
#include <hip/hip_runtime.h>
#include <math.h>

#define EPSQ 1e-7f
#define TDIM 2000
#define CDIM 128
#define LDIM 200
#define SPL  7
#define SENTE (-(1 << 30))

// ---- LDS int-index map (per block: ONE stream - alpha or beta) ----
// RAW  : 0..2047      (8KB)  producer scratch, 8 pairs x 256 floats
// LABSI: 2048..2247   labels
// PRODF1 2248, PRODF2 2249, CONSF 2250
// ARR  : 2304..35071  (128KB) arranged ring: 64 rows x 512 floats (2KB/row)
//        row layout: [lane*4 floats j=0..3][1KB][lane*4 floats j=4..6+pad]
#define LABSI 2048
#define PRODF1 2248
#define PRODF2 2249
#define CONSF 2250
#define ARRB  9216      // byte offset of ARR
#define SMEMN 35072     // ints = 140288 B

__device__ __forceinline__ float dpp_shr_f(float x) { // lane i <- lane i-1, lane0 <- 0
    return __int_as_float(__builtin_amdgcn_update_dpp(0, __float_as_int(x), 0x138, 0xf, 0xf, true));
}
__device__ __forceinline__ int dpp_shr_i(int x) {
    return __builtin_amdgcn_update_dpp(0, x, 0x138, 0xf, 0xf, true);
}
__device__ __forceinline__ float dpp_shl_f(float x) { // lane i <- lane i+1, lane63 <- 0
    return __int_as_float(__builtin_amdgcn_update_dpp(0, __float_as_int(x), 0x130, 0xf, 0xf, true));
}
__device__ __forceinline__ int dpp_shl_i(int x) {
    return __builtin_amdgcn_update_dpp(0, x, 0x130, 0xf, 0xf, true);
}

// ---- alpha renorm (verified): per-lane BFP, neighbor = lane-1
__device__ __forceinline__ void renorm_alpha(float a[SPL], int& E, float& fprev, int lane) {
    float mx = fmaxf(fmaxf(fmaxf(a[0], a[1]), fmaxf(a[2], a[3])),
                     fmaxf(fmaxf(a[4], a[5]), a[6]));
    bool zero = (mx == 0.f);
    int e = ((__float_as_int(mx) >> 23) & 0xff) - 127;
    int S_self = zero ? SENTE : (E + e);
    int S1 = dpp_shr_i(S_self);
    if (lane == 0) S1 = SENTE;
    int S2 = dpp_shr_i(S1);
    if (lane == 0) S2 = SENTE;
    int E_new = max(S_self, S1);
    int E_prevnew = max(S1, S2);
    int dg = E - E_new;
    float g = (zero || dg < -126) ? 0.f : __int_as_float((dg + 127) << 23);
#pragma unroll
    for (int j = 0; j < SPL; ++j) a[j] *= g;
    E = E_new;
    int df = E_prevnew - E_new;
    bool fz = (E_prevnew <= SENTE / 2) || (df < -126);
    if (df > 126) df = 126;
    fprev = fz ? 0.f : __int_as_float((df + 127) << 23);
}

// ---- beta renorm: mirror, neighbor = lane+1
__device__ __forceinline__ void renorm_beta(float b[SPL], int& E, float& fnext, int lane) {
    float mx = fmaxf(fmaxf(fmaxf(b[0], b[1]), fmaxf(b[2], b[3])),
                     fmaxf(fmaxf(b[4], b[5]), b[6]));
    bool zero = (mx == 0.f);
    int e = ((__float_as_int(mx) >> 23) & 0xff) - 127;
    int S_self = zero ? SENTE : (E + e);
    int S1 = dpp_shl_i(S_self);
    if (lane == 63) S1 = SENTE;
    int S2 = dpp_shl_i(S1);
    if (lane == 63) S2 = SENTE;
    int E_new = max(S_self, S1);
    int E_nextnew = max(S1, S2);
    int dg = E - E_new;
    float g = (zero || dg < -126) ? 0.f : __int_as_float((dg + 127) << 23);
#pragma unroll
    for (int j = 0; j < SPL; ++j) b[j] *= g;
    E = E_new;
    int df = E_nextnew - E_new;
    bool fz = (E_nextnew <= SENTE / 2) || (df < -126);
    if (df > 126) df = 126;
    fnext = fz ? 0.f : __int_as_float((df + 127) << 23);
}

// arranged-ring read: X is a byte-offset constant-expr (< 131072)
#define ARD(X) (*(const float4*)((((X) < 65536) ? arC : arC2) + ((X) & 65535)))

// alpha MAIN step (t%64==1): consume reg slot (1+TOFF)&3 (row t+TOFF),
// prefetch row t+TOFF+3 (ARR slot (TOFF+4)&63) -> reg slot (TOFF)&3.
#define APB(TOFF) (((((TOFF)+4)&63))<<11)
#define A_STEPF(TOFF) do {                                                    \
    float p6 = dpp_shr_f(a[6]) * fprev;                                       \
    float p5 = dpp_shr_f(a[5]) * fprev;                                       \
    float4 qa = qA[(1+(TOFF))&3], qb = qB[(1+(TOFF))&3];                      \
    float n0 = fmaf(skipf[0], p5,   a[0] + p6)   * qa.x;                      \
    float n1 = fmaf(skipf[1], p6,   a[1] + a[0]) * qa.y;                      \
    float n2 = fmaf(skipf[2], a[0], a[2] + a[1]) * qa.z;                      \
    float n3 = fmaf(skipf[3], a[1], a[3] + a[2]) * qa.w;                      \
    float n4 = fmaf(skipf[4], a[2], a[4] + a[3]) * qb.x;                      \
    float n5 = fmaf(skipf[5], a[3], a[5] + a[4]) * qb.y;                      \
    float n6 = fmaf(skipf[6], a[4], a[6] + a[5]) * qb.z;                      \
    a[0]=n0; a[1]=n1; a[2]=n2; a[3]=n3; a[4]=n4; a[5]=n5; a[6]=n6;            \
    qA[(TOFF)&3] = ARD(APB(TOFF));                                            \
    qB[(TOFF)&3] = ARD(APB(TOFF)+1024);                                       \
} while (0);

// alpha TAIL step (t%4==1, dynamic ARR slot, with capture)
#define A_TAIL(TOFF) do {                                                     \
    float p6 = dpp_shr_f(a[6]) * fprev;                                       \
    float p5 = dpp_shr_f(a[5]) * fprev;                                       \
    float4 qa = qA[(1+(TOFF))&3], qb = qB[(1+(TOFF))&3];                      \
    float n0 = fmaf(skipf[0], p5,   a[0] + p6)   * qa.x;                      \
    float n1 = fmaf(skipf[1], p6,   a[1] + a[0]) * qa.y;                      \
    float n2 = fmaf(skipf[2], a[0], a[2] + a[1]) * qa.z;                      \
    float n3 = fmaf(skipf[3], a[1], a[3] + a[2]) * qa.w;                      \
    float n4 = fmaf(skipf[4], a[2], a[4] + a[3]) * qb.x;                      \
    float n5 = fmaf(skipf[5], a[3], a[5] + a[4]) * qb.y;                      \
    float n6 = fmaf(skipf[6], a[4], a[6] + a[5]) * qb.z;                      \
    a[0]=n0; a[1]=n1; a[2]=n2; a[3]=n3; a[4]=n4; a[5]=n5; a[6]=n6;            \
    if (t + (TOFF) == m) {                                                    \
        _Pragma("unroll")                                                     \
        for (int j = 0; j < SPL; ++j) ac[j] = a[j];                           \
        Eac = E;                                                              \
    }                                                                         \
    {   int ro_ = ((t + (TOFF) + 3) & 63) << 11;                              \
        qA[(TOFF)&3] = *(const float4*)(arC + ro_);                           \
        qB[(TOFF)&3] = *(const float4*)(arC + ro_ + 1024); }                  \
} while (0);

// beta MAIN step (s%64==0): consume reg slot (SOFF)&3 (j = s+SOFF),
// prefetch j+3 (ARR slot (SOFF+3)&63) -> reg slot (3+SOFF)&3.
#define BPB(SOFF) (((((SOFF)+3)&63))<<11)
#define B_STEPF(SOFF) do {                                                    \
    float4 qa = qA[(SOFF)&3], qb = qB[(SOFF)&3];                              \
    float c0 = bb[0]*qa.x, c1 = bb[1]*qa.y;                                   \
    float c2 = bb[2]*qa.z, c3 = bb[3]*qa.w;                                   \
    float c4 = bb[4]*qb.x, c5 = bb[5]*qb.y;                                   \
    float c6 = bb[6]*qb.z;                                                    \
    float cn0 = dpp_shl_f(c0) * fnext;                                        \
    float cn1 = dpp_shl_f(c1) * fnext;                                        \
    bb[0] = fmaf(skb[0], c2, c0 + c1);                                        \
    bb[1] = fmaf(skb[1], c3, c1 + c2);                                        \
    bb[2] = fmaf(skb[2], c4, c2 + c3);                                        \
    bb[3] = fmaf(skb[3], c5, c3 + c4);                                        \
    bb[4] = fmaf(skb[4], c6, c4 + c5);                                        \
    bb[5] = fmaf(skb[5], cn0, c5 + c6);                                       \
    bb[6] = fmaf(skb[6], cn1, c6 + cn0);                                      \
    qA[(3+(SOFF))&3] = ARD(BPB(SOFF));                                        \
    qB[(3+(SOFF))&3] = ARD(BPB(SOFF)+1024);                                   \
} while (0);

// beta TAIL step (s%4==0, dynamic slot, with capture)
#define B_TAIL(SOFF) do {                                                     \
    float4 qa = qA[(SOFF)&3], qb = qB[(SOFF)&3];                              \
    float c0 = bb[0]*qa.x, c1 = bb[1]*qa.y;                                   \
    float c2 = bb[2]*qa.z, c3 = bb[3]*qa.w;                                   \
    float c4 = bb[4]*qb.x, c5 = bb[5]*qb.y;                                   \
    float c6 = bb[6]*qb.z;                                                    \
    float cn0 = dpp_shl_f(c0) * fnext;                                        \
    float cn1 = dpp_shl_f(c1) * fnext;                                        \
    bb[0] = fmaf(skb[0], c2, c0 + c1);                                        \
    bb[1] = fmaf(skb[1], c3, c1 + c2);                                        \
    bb[2] = fmaf(skb[2], c4, c2 + c3);                                        \
    bb[3] = fmaf(skb[3], c5, c3 + c4);                                        \
    bb[4] = fmaf(skb[4], c6, c4 + c5);                                        \
    bb[5] = fmaf(skb[5], cn0, c5 + c6);                                       \
    bb[6] = fmaf(skb[6], cn1, c6 + cn0);                                      \
    if (s + (SOFF) == scap) {                                                 \
        _Pragma("unroll")                                                     \
        for (int j = 0; j < SPL; ++j) bc[j] = bb[j];                          \
        Ebc = E;                                                              \
    }                                                                         \
    {   int ro_ = ((s + (SOFF) + 3) & 63) << 11;                              \
        qA[(3+(SOFF))&3] = *(const float4*)(arC + ro_);                       \
        qB[(3+(SOFF))&3] = *(const float4*)(arC + ro_ + 1024); }              \
} while (0);

#define ABLK(T) renorm_alpha(a, E, fprev, lane); \
    A_STEPF(T) A_STEPF((T)+1) A_STEPF((T)+2) A_STEPF((T)+3)
#define BBLK(T) renorm_beta(bb, E, fnext, lane); \
    B_STEPF(T) B_STEPF((T)+1) B_STEPF((T)+2) B_STEPF((T)+3)

#define WAITP(NEED) do { int nd_ = (NEED);                                    \
    while (vsm[PRODF1] < nd_ || vsm[PRODF2] < nd_)                            \
        __builtin_amdgcn_s_sleep(1);                                          \
    asm volatile("" ::: "memory"); } while (0)

// ---- producer macros (P4 = 0 or 4 = pair offset within group) ----
#define LOADG(W, G) do {                                                      \
    _Pragma("unroll")                                                         \
    for (int k_ = 0; k_ < 4; ++k_) {                                          \
        int ii_ = (G) * 8 + P4 + k_; if (ii_ > iend) ii_ = iend;              \
        int pr_ = role ? (pbase - ii_) : ii_;                                 \
        W[k_] = rp4[pr_ * 64 + lane];                                         \
    }                                                                         \
} while (0)

#define STORERAW(W) do {                                                      \
    _Pragma("unroll")                                                         \
    for (int k_ = 0; k_ < 4; ++k_) {                                          \
        float4 x_ = W[k_];                                                    \
        x_.x += EPSQ; x_.y += EPSQ; x_.z += EPSQ; x_.w += EPSQ;               \
        *(float4*)(rawWB + k_ * 1024 + (lane << 4)) = x_;                     \
    }                                                                         \
} while (0)

#define GATH(RI, A, B) do {                                                   \
    A.x = rdF[((RI) << 7) + cls[0]]; A.y = rdF[((RI) << 7) + cls[1]];         \
    A.z = rdF[((RI) << 7) + cls[2]]; A.w = rdF[((RI) << 7) + cls[3]];         \
    B.x = rdF[((RI) << 7) + cls[4]]; B.y = rdF[((RI) << 7) + cls[5]];         \
    B.z = rdF[((RI) << 7) + cls[6]]; B.w = B.z;                               \
} while (0)

// FIXED (r3 bug): slot must come from the ACTUAL pair index (pbase - item)
// for the descending beta stream, not the item index. Also suppress the
// out-of-range row Tbm1+1 (present when Tbm1 even) so it cannot alias slot 63.
#define WRARR(R, A, B) do {                                                   \
    int pi_ = g8 + P4 + ((R) >> 1); if (pi_ > iend) pi_ = iend;               \
    int pr_ = role ? (pbase - pi_) : pi_;                                     \
    int row_ = 2 * pr_ + ((R) & 1);                                           \
    if (!role || row_ <= Tbm1) {                                              \
        int sl_ = role ? ((Tbm1 - row_) & 63) : (row_ & 63);                  \
        char* d_ = arrWB + (sl_ << 11) + (lane << 4);                         \
        *(float4*)d_ = A; *(float4*)(d_ + 1024) = B;                          \
    }                                                                         \
} while (0)

#define PGROUP(G) do { int g8 = 8 * (G);                                      \
    GATH(0, A0, B0); GATH(1, A1, B1);                                         \
    WRARR(0, A0, B0); GATH(2, A0, B0);                                        \
    WRARR(1, A1, B1); GATH(3, A1, B1);                                        \
    WRARR(2, A0, B0); GATH(4, A0, B0);                                        \
    WRARR(3, A1, B1); GATH(5, A1, B1);                                        \
    WRARR(4, A0, B0); GATH(6, A0, B0);                                        \
    WRARR(5, A1, B1); GATH(7, A1, B1);                                        \
    WRARR(6, A0, B0); WRARR(7, A1, B1);                                       \
} while (0)

__global__ void __launch_bounds__(192, 1)
__attribute__((amdgpu_waves_per_eu(1, 1)))
ctc_kernel(const float* __restrict__ y_pred,
           const int* __restrict__ labels,
           const int* __restrict__ feat_lens,
           const int* __restrict__ label_lens,
           float* __restrict__ ws)
{
    __shared__ int smem[SMEMN];
    float* smf = (float*)smem;
    volatile int* vsm = (volatile int*)smem;

    const int bid = blockIdx.x;
    const int b = bid >> 1;
    const int role = bid & 1;          // 0 = alpha block, 1 = beta block
    const int tid = threadIdx.x;
    const int lane = tid & 63;
    const int wv = tid >> 6;           // 0 = consumer, 1/2 = producers

    int f = feat_lens[b];
    f = (f + 1) >> 1; f = (f + 1) >> 1;
    const int Tbm1 = f - 1;
    const int m = f >> 1;             // alpha: steps 1..m; beta: rows Tbm1..m+1

    if (tid < 3) smem[PRODF1 + tid] = 0;
    const int* labrow = labels + b * LDIM;
    for (int i = tid; i < LDIM; i += 192) smem[LABSI + i] = labrow[i];
    __syncthreads();

    // per-lane state tables (needed by consumer AND producers)
    int cls[SPL]; float skipf[SPL];
    const int s0 = lane * SPL;
#pragma unroll
    for (int j = 0; j < SPL; ++j) {
        int s = s0 + j;
        int c = CDIM - 1; float sk = 0.f;
        if (s < (2 * LDIM + 1) && (s & 1)) {
            int kk = s >> 1;
            c = smem[LABSI + kk];
            if (kk >= 1 && smem[LABSI + kk] != smem[LABSI + kk - 1]) sk = 1.f;
        }
        cls[j] = c; skipf[j] = sk;
    }

    const float4* rp4 = (const float4*)(y_pred + (size_t)b * TDIM * CDIM);

    if (wv != 0) {
        // =============== producers: stage + gather + arrange ===============
        const int P4 = (wv - 1) * 4;
        char* rawWB = (char*)smem + (P4 << 10);
        const float* rdF = smf + (P4 << 8);
        char* arrWB = (char*)smem + ARRB;
        int iend, pbase;
        if (role == 0) { iend = (m + 18) >> 1; pbase = 0; }
        else {
            const int pstart = Tbm1 >> 1;
            int pl = (m - 18) >> 1; if (pl < 0) pl = 0;
            iend = pstart - pl; pbase = pstart;
        }
        const int ng = (iend >> 3) + 1;
        const int PF = (wv == 1) ? PRODF1 : PRODF2;
        float4 w0[4], w1[4];
        float4 A0, B0, A1, B1;
        LOADG(w0, 0);
        if (ng > 1) LOADG(w1, 1);
        int g = 0;
        while (true) {
            while (vsm[CONSF] + 32 < 8 * (g + 1)) __builtin_amdgcn_s_sleep(2);
            asm volatile("" ::: "memory");
            STORERAW(w0);
            asm volatile("s_waitcnt lgkmcnt(0)" ::: "memory");
            PGROUP(g);
            asm volatile("s_waitcnt lgkmcnt(0)" ::: "memory");
            vsm[PF] = 8 * (g + 1);
            if (g + 2 < ng) LOADG(w0, g + 2);
            ++g; if (g >= ng) break;
            while (vsm[CONSF] + 32 < 8 * (g + 1)) __builtin_amdgcn_s_sleep(2);
            asm volatile("" ::: "memory");
            STORERAW(w1);
            asm volatile("s_waitcnt lgkmcnt(0)" ::: "memory");
            PGROUP(g);
            asm volatile("s_waitcnt lgkmcnt(0)" ::: "memory");
            vsm[PF] = 8 * (g + 1);
            if (g + 2 < ng) LOADG(w1, g + 2);
            ++g; if (g >= ng) break;
        }
        return;
    }

    // ======================== consumer ========================
    const char* arC  = (const char*)smem + ARRB + (lane << 4);
    const char* arC2 = arC + 65536;
    const int llen = label_lens[b];
    const int i1 = 2 * llen - 1, i2 = 2 * llen;

    if (role == 0) {
        // ================= alpha (t = 0..m) =================
        float a[SPL], ac[SPL];
        float4 qA[4], qB[4];
        int E = 0, Eac = 0;
        float fprev = 0.f;
#pragma unroll
        for (int j = 0; j < SPL; ++j) { a[j] = 0.f; ac[j] = 0.f; }

        WAITP(2);
        qA[0] = ARD(0);    qB[0] = ARD(1024);
        qA[1] = ARD(2048); qB[1] = ARD(2048+1024);
        qA[2] = ARD(4096); qB[2] = ARD(4096+1024);
        qA[3] = ARD(6144); qB[3] = ARD(6144+1024);
        if (lane == 0) { a[0] = qA[0].x; a[1] = qA[0].y; }

        int t = 1;
        // -------- main: 64 steps/iter, branch-free, static offsets ------
        while (t + 64 <= m) {
            vsm[CONSF] = (t >= 2) ? (((t - 2) >> 1) + 1) : 0;
            WAITP(((t + 34) >> 1) + 1);
            ABLK(0) ABLK(4) ABLK(8) ABLK(12)
            ABLK(16) ABLK(20) ABLK(24) ABLK(28)
            {
                int tc = t + 32;
                vsm[CONSF] = ((tc - 2) >> 1) + 1;
                WAITP(((tc + 34) >> 1) + 1);
            }
            ABLK(32) ABLK(36) ABLK(40) ABLK(44)
            ABLK(48) ABLK(52) ABLK(56) ABLK(60)
            t += 64;
        }
        // -------- tail: 16 steps/iter with capture ------
        while (t <= m) {
            vsm[CONSF] = (t >= 2) ? (((t - 2) >> 1) + 1) : 0;
            WAITP(((t + 18) >> 1) + 1);
            renorm_alpha(a, E, fprev, lane);
            A_TAIL(0) A_TAIL(1) A_TAIL(2) A_TAIL(3)
            renorm_alpha(a, E, fprev, lane);
            A_TAIL(4) A_TAIL(5) A_TAIL(6) A_TAIL(7)
            renorm_alpha(a, E, fprev, lane);
            A_TAIL(8) A_TAIL(9) A_TAIL(10) A_TAIL(11)
            renorm_alpha(a, E, fprev, lane);
            A_TAIL(12) A_TAIL(13) A_TAIL(14) A_TAIL(15)
            t += 16;
        }
        vsm[CONSF] = 1 << 28;
        asm volatile("" ::: "memory");
        float* wsb = ws + (size_t)b * 1024;
#pragma unroll
        for (int j = 0; j < SPL; ++j) wsb[lane * SPL + j] = ac[j];
        ((int*)wsb)[448 + lane] = Eac;
    } else {
        // ================= beta (rows Tbm1 down to m+1) =================
        float bb[SPL], bc[SPL];
        float4 qA[4], qB[4];
        int E = 0, Ebc = 0;
        float fnext = 0.f;
#pragma unroll
        for (int j = 0; j < SPL; ++j) {
            int s = s0 + j;
            bb[j] = (s == i1 || s == i2) ? 1.f : 0.f;
            bc[j] = 0.f;
        }
        float skb[SPL];
#pragma unroll
        for (int j = 0; j < 5; ++j) skb[j] = skipf[j + 2];
        skb[5] = (lane == 63) ? 0.f : __shfl_down(skipf[0], 1, 64);
        skb[6] = (lane == 63) ? 0.f : __shfl_down(skipf[1], 1, 64);

        const int t0 = Tbm1;
        const int nb = t0 - m;       // number of steps (>= 1)
        const int scap = nb - 1;
        const int pstart = t0 >> 1;

        WAITP(2);
        qA[0] = ARD(0);    qB[0] = ARD(1024);
        qA[1] = ARD(2048); qB[1] = ARD(2048+1024);
        qA[2] = ARD(4096); qB[2] = ARD(4096+1024);
        qA[3] = make_float4(0.f,0.f,0.f,0.f); qB[3] = qA[3];

        int s = 0;
        // -------- main: 64 steps/iter, branch-free, static offsets ------
        while (s + 64 <= scap) {
            {
                int tcur = t0 - s;
                vsm[CONSF] = pstart - ((tcur + 2) >> 1) + 1;
                WAITP(pstart - ((tcur - 34) >> 1) + 1);
            }
            BBLK(0) BBLK(4) BBLK(8) BBLK(12)
            BBLK(16) BBLK(20) BBLK(24) BBLK(28)
            {
                int tcur = t0 - s - 32;
                vsm[CONSF] = pstart - ((tcur + 2) >> 1) + 1;
                WAITP(pstart - ((tcur - 34) >> 1) + 1);
            }
            BBLK(32) BBLK(36) BBLK(40) BBLK(44)
            BBLK(48) BBLK(52) BBLK(56) BBLK(60)
            s += 64;
        }
        // -------- tail: 16 steps/iter with capture ------
        while (s < nb) {
            int tcur = t0 - s;
            vsm[CONSF] = pstart - ((tcur + 2) >> 1) + 1;
            WAITP(pstart - ((tcur - 18) >> 1) + 1);
            renorm_beta(bb, E, fnext, lane);
            B_TAIL(0) B_TAIL(1) B_TAIL(2) B_TAIL(3)
            renorm_beta(bb, E, fnext, lane);
            B_TAIL(4) B_TAIL(5) B_TAIL(6) B_TAIL(7)
            renorm_beta(bb, E, fnext, lane);
            B_TAIL(8) B_TAIL(9) B_TAIL(10) B_TAIL(11)
            renorm_beta(bb, E, fnext, lane);
            B_TAIL(12) B_TAIL(13) B_TAIL(14) B_TAIL(15)
            s += 16;
        }
        vsm[CONSF] = 1 << 28;
        asm volatile("" ::: "memory");
        float* wsb = ws + (size_t)b * 1024 + 512;
#pragma unroll
        for (int j = 0; j < SPL; ++j) wsb[lane * SPL + j] = bc[j];
        ((int*)wsb)[448 + lane] = Ebc;
    }
}

__global__ void __launch_bounds__(64, 1)
ctc_combine(const float* __restrict__ ws, float* __restrict__ out)
{
    const int b = blockIdx.x;
    const int lane = threadIdx.x & 63;
    const float* wa = ws + (size_t)b * 1024;
    const float* wb = wa + 512;
    const int Ea = ((const int*)wa)[448 + lane];
    const int Eb = ((const int*)wb)[448 + lane];
    float dot = 0.f;
#pragma unroll
    for (int j = 0; j < SPL; ++j)
        dot = fmaf(wa[lane * SPL + j], wb[lane * SPL + j], dot);
    float l2 = (dot > 0.f) ? (log2f(dot) + (float)(Ea + Eb)) : -1e30f;
    float M = l2;
#pragma unroll
    for (int d = 1; d < 64; d <<= 1) M = fmaxf(M, __shfl_xor(M, d, 64));
    float S = exp2f(l2 - M);
#pragma unroll
    for (int d = 1; d < 64; d <<= 1) S += __shfl_xor(S, d, 64);
    if (lane == 0) out[b] = -(M + log2f(S)) * 0.69314718055994530942f;
}

extern "C" void kernel_launch(void* const* d_in, const int* in_sizes, int n_in,
                              void* d_out, int out_size, void* d_ws, size_t ws_size,
                              hipStream_t stream) {
    (void)n_in; (void)out_size; (void)ws_size;
    const float* y_pred     = (const float*)d_in[0];
    const int*   labels     = (const int*)d_in[1];
    const int*   feat_lens  = (const int*)d_in[2];
    const int*   label_lens = (const int*)d_in[3];
    float* out = (float*)d_out;
    float* ws  = (float*)d_ws;
    const int B = in_sizes[2];  // 128
    ctc_kernel<<<B * 2, 192, 0, stream>>>(y_pred, labels, feat_lens, label_lens, ws);
    ctc_combine<<<B, 64, 0, stream>>>(ws, out);
}

// Round 5
// 265.462 us; speedup vs baseline: 1.0067x; 1.0067x over previous
//
#include <hip/hip_runtime.h>
#include <math.h>

#define EPSQ 1e-7f
#define TDIM 2000
#define CDIM 128
#define LDIM 200
#define SPL  8
#define SENTE (-(1 << 30))

// LDS: ring 64 rows x 128 floats = 8192 floats (32KB), then labels.
#define LABSI 8192
#define SMEMN 8400

__device__ __forceinline__ float dpp_shr_f(float x) { // lane i <- lane i-1, lane0 <- 0
    return __int_as_float(__builtin_amdgcn_update_dpp(0, __float_as_int(x), 0x138, 0xf, 0xf, true));
}
__device__ __forceinline__ int dpp_shr_i(int x) {
    return __builtin_amdgcn_update_dpp(0, x, 0x138, 0xf, 0xf, true);
}
__device__ __forceinline__ float dpp_shl_f(float x) { // lane i <- lane i+1, lane63 <- 0
    return __int_as_float(__builtin_amdgcn_update_dpp(0, __float_as_int(x), 0x130, 0xf, 0xf, true));
}
__device__ __forceinline__ int dpp_shl_i(int x) {
    return __builtin_amdgcn_update_dpp(0, x, 0x130, 0xf, 0xf, true);
}

// ---- alpha renorm (verified logic, widened to 8): per-lane BFP, neighbor = lane-1
__device__ __forceinline__ void renorm_alpha(float a[SPL], int& E, float& fprev, int lane) {
    float mx = fmaxf(fmaxf(fmaxf(a[0], a[1]), fmaxf(a[2], a[3])),
                     fmaxf(fmaxf(a[4], a[5]), fmaxf(a[6], a[7])));
    bool zero = (mx == 0.f);
    int e = ((__float_as_int(mx) >> 23) & 0xff) - 127;
    int S_self = zero ? SENTE : (E + e);
    int S1 = dpp_shr_i(S_self);
    if (lane == 0) S1 = SENTE;
    int S2 = dpp_shr_i(S1);
    if (lane == 0) S2 = SENTE;
    int E_new = max(S_self, S1);
    int E_prevnew = max(S1, S2);
    int dg = E - E_new;
    float g = (zero || dg < -126) ? 0.f : __int_as_float((dg + 127) << 23);
#pragma unroll
    for (int j = 0; j < SPL; ++j) a[j] *= g;
    E = E_new;
    int df = E_prevnew - E_new;
    bool fz = (E_prevnew <= SENTE / 2) || (df < -126);
    if (df > 126) df = 126;
    fprev = fz ? 0.f : __int_as_float((df + 127) << 23);
}

// ---- beta renorm: mirror, neighbor = lane+1
__device__ __forceinline__ void renorm_beta(float b[SPL], int& E, float& fnext, int lane) {
    float mx = fmaxf(fmaxf(fmaxf(b[0], b[1]), fmaxf(b[2], b[3])),
                     fmaxf(fmaxf(b[4], b[5]), fmaxf(b[6], b[7])));
    bool zero = (mx == 0.f);
    int e = ((__float_as_int(mx) >> 23) & 0xff) - 127;
    int S_self = zero ? SENTE : (E + e);
    int S1 = dpp_shl_i(S_self);
    if (lane == 63) S1 = SENTE;
    int S2 = dpp_shl_i(S1);
    if (lane == 63) S2 = SENTE;
    int E_new = max(S_self, S1);
    int E_nextnew = max(S1, S2);
    int dg = E - E_new;
    float g = (zero || dg < -126) ? 0.f : __int_as_float((dg + 127) << 23);
#pragma unroll
    for (int j = 0; j < SPL; ++j) b[j] *= g;
    E = E_new;
    int df = E_nextnew - E_new;
    bool fz = (E_nextnew <= SENTE / 2) || (df < -126);
    if (df > 126) df = 126;
    fnext = fz ? 0.f : __int_as_float((df + 127) << 23);
}

#define RA renorm_alpha(a, E, fprev, lane);
#define RB renorm_beta(bb, E, fnext, lane);

// ===== alpha step. SPL=8, s0=8*lane even => even-j states are blank (col 127,
// skip=0); odd-j states are labels kk=4*lane+u. Cross-lane: only p7 = prev a[7]
// (state s0-1) is needed (skip(s0)=0 structurally).
// Main (t%64==1): consume reg slot (1+CT)&3 (row t+CT), prefetch row t+CT+3
// (ring slot (CT+4)&63, static) into reg slot (CT)&3.
#define A_STEPF(CT) do {                                                      \
    const int cs_ = (1+(CT))&3;                                               \
    float p7 = dpp_shr_f(a[7]) * fprev;                                       \
    float n0 = (a[0] + p7) * qb[cs_];                                         \
    float n1 = fmaf(sk1, p7, a[1] + a[0]) * ql[cs_][0];                       \
    float n2 = (a[2] + a[1]) * qb[cs_];                                       \
    float n3 = fmaf(sk3, a[1], a[3] + a[2]) * ql[cs_][1];                     \
    float n4 = (a[4] + a[3]) * qb[cs_];                                       \
    float n5 = fmaf(sk5, a[3], a[5] + a[4]) * ql[cs_][2];                     \
    float n6 = (a[6] + a[5]) * qb[cs_];                                       \
    float n7 = fmaf(sk7, a[5], a[7] + a[6]) * ql[cs_][3];                     \
    a[0]=n0;a[1]=n1;a[2]=n2;a[3]=n3;a[4]=n4;a[5]=n5;a[6]=n6;a[7]=n7;          \
    { const int ro_ = (((CT)+4)&63)<<7;                                       \
      qb[(CT)&3]    = ringF[ro_ + 127];                                       \
      ql[(CT)&3][0] = ringF[ro_ + cl0];                                       \
      ql[(CT)&3][1] = ringF[ro_ + cl1];                                       \
      ql[(CT)&3][2] = ringF[ro_ + cl2];                                       \
      ql[(CT)&3][3] = ringF[ro_ + cl3]; }                                     \
} while (0);

#define A_TAIL(CT) do {                                                       \
    const int cs_ = (1+(CT))&3;                                               \
    float p7 = dpp_shr_f(a[7]) * fprev;                                       \
    float n0 = (a[0] + p7) * qb[cs_];                                         \
    float n1 = fmaf(sk1, p7, a[1] + a[0]) * ql[cs_][0];                       \
    float n2 = (a[2] + a[1]) * qb[cs_];                                       \
    float n3 = fmaf(sk3, a[1], a[3] + a[2]) * ql[cs_][1];                     \
    float n4 = (a[4] + a[3]) * qb[cs_];                                       \
    float n5 = fmaf(sk5, a[3], a[5] + a[4]) * ql[cs_][2];                     \
    float n6 = (a[6] + a[5]) * qb[cs_];                                       \
    float n7 = fmaf(sk7, a[5], a[7] + a[6]) * ql[cs_][3];                     \
    a[0]=n0;a[1]=n1;a[2]=n2;a[3]=n3;a[4]=n4;a[5]=n5;a[6]=n6;a[7]=n7;          \
    if (t + (CT) == m) {                                                      \
        _Pragma("unroll")                                                     \
        for (int j = 0; j < SPL; ++j) ac[j] = a[j];                           \
        Eac = E;                                                              \
    }                                                                         \
    { const int ro_ = ((t+(CT)+3)&63)<<7;                                     \
      qb[(CT)&3]    = ringF[ro_ + 127];                                       \
      ql[(CT)&3][0] = ringF[ro_ + cl0];                                       \
      ql[(CT)&3][1] = ringF[ro_ + cl1];                                       \
      ql[(CT)&3][2] = ringF[ro_ + cl2];                                       \
      ql[(CT)&3][3] = ringF[ro_ + cl3]; }                                     \
} while (0);

// ===== beta step: bb_j = c_j + c_{j+1} + skip(s+2)*c_{j+2}; even j -> skip 0.
// skb for j=1,3,5 are sk3,sk5,sk7; j=7 needs next lane's sk1 (skb7).
// Main (s%64==0): consume slot (CT)&3 (j = s+CT), prefetch j+3 (ring slot
// (CT+3)&63, static) into reg slot (3+CT)&3.
#define B_STEPF(CT) do {                                                      \
    const int cs_ = (CT)&3;                                                   \
    float c0 = bb[0]*qb[cs_],    c1 = bb[1]*ql[cs_][0];                       \
    float c2 = bb[2]*qb[cs_],    c3 = bb[3]*ql[cs_][1];                       \
    float c4 = bb[4]*qb[cs_],    c5 = bb[5]*ql[cs_][2];                       \
    float c6 = bb[6]*qb[cs_],    c7 = bb[7]*ql[cs_][3];                       \
    float cn0 = dpp_shl_f(c0) * fnext;                                        \
    float cn1 = dpp_shl_f(c1) * fnext;                                        \
    bb[0] = c0 + c1;                                                          \
    bb[1] = fmaf(sk3, c3, c1 + c2);                                           \
    bb[2] = c2 + c3;                                                          \
    bb[3] = fmaf(sk5, c5, c3 + c4);                                           \
    bb[4] = c4 + c5;                                                          \
    bb[5] = fmaf(sk7, c7, c5 + c6);                                           \
    bb[6] = c6 + c7;                                                          \
    bb[7] = fmaf(skb7, cn1, c7 + cn0);                                        \
    { const int ro_ = (((CT)+3)&63)<<7;                                       \
      qb[(3+(CT))&3]    = ringF[ro_ + 127];                                   \
      ql[(3+(CT))&3][0] = ringF[ro_ + cl0];                                   \
      ql[(3+(CT))&3][1] = ringF[ro_ + cl1];                                   \
      ql[(3+(CT))&3][2] = ringF[ro_ + cl2];                                   \
      ql[(3+(CT))&3][3] = ringF[ro_ + cl3]; }                                 \
} while (0);

#define B_TAIL(CT) do {                                                       \
    const int cs_ = (CT)&3;                                                   \
    float c0 = bb[0]*qb[cs_],    c1 = bb[1]*ql[cs_][0];                       \
    float c2 = bb[2]*qb[cs_],    c3 = bb[3]*ql[cs_][1];                       \
    float c4 = bb[4]*qb[cs_],    c5 = bb[5]*ql[cs_][2];                       \
    float c6 = bb[6]*qb[cs_],    c7 = bb[7]*ql[cs_][3];                       \
    float cn0 = dpp_shl_f(c0) * fnext;                                        \
    float cn1 = dpp_shl_f(c1) * fnext;                                        \
    bb[0] = c0 + c1;                                                          \
    bb[1] = fmaf(sk3, c3, c1 + c2);                                           \
    bb[2] = c2 + c3;                                                          \
    bb[3] = fmaf(sk5, c5, c3 + c4);                                           \
    bb[4] = c4 + c5;                                                          \
    bb[5] = fmaf(sk7, c7, c5 + c6);                                           \
    bb[6] = c6 + c7;                                                          \
    bb[7] = fmaf(skb7, cn1, c7 + cn0);                                        \
    if (s + (CT) == scap) {                                                   \
        _Pragma("unroll")                                                     \
        for (int j = 0; j < SPL; ++j) bc[j] = bb[j];                          \
        Ebc = E;                                                              \
    }                                                                         \
    { const int ro_ = ((s+(CT)+3)&63)<<7;                                     \
      qb[(3+(CT))&3]    = ringF[ro_ + 127];                                   \
      ql[(3+(CT))&3][0] = ringF[ro_ + cl0];                                   \
      ql[(3+(CT))&3][1] = ringF[ro_ + cl1];                                   \
      ql[(3+(CT))&3][2] = ringF[ro_ + cl2];                                   \
      ql[(3+(CT))&3][3] = ringF[ro_ + cl3]; }                                 \
} while (0);

#define A4(T)  A_STEPF(T) A_STEPF((T)+1) A_STEPF((T)+2) A_STEPF((T)+3)
#define A16(T) RA A4(T) RA A4((T)+4) RA A4((T)+8) RA A4((T)+12)
#define AT4(T) A_TAIL(T) A_TAIL((T)+1) A_TAIL((T)+2) A_TAIL((T)+3)
#define B4(T)  B_STEPF(T) B_STEPF((T)+1) B_STEPF((T)+2) B_STEPF((T)+3)
#define B16(T) RB B4(T) RB B4((T)+4) RB B4((T)+8) RB B4((T)+12)
#define BT4(T) B_TAIL(T) B_TAIL((T)+1) B_TAIL((T)+2) B_TAIL((T)+3)

// ---- self-staging (same wave). Chunk = 8 pairs = 16 rows. At chunk k:
// issue loads for k+2 (counted vmcnt via compiler), eps+write k+1, consume k.
#define A_LOAD(W, KC) do { const int b_ = 8*(KC);                             \
    _Pragma("unroll") for (int i_ = 0; i_ < 8; ++i_) {                        \
        int pi_ = b_ + i_; if (pi_ > pend) pi_ = pend;                        \
        W[i_] = rp4[(size_t)pi_*64 + lane]; } } while(0)
#define A_WRITE(W, KC) do { const int b_ = 8*(KC);                            \
    _Pragma("unroll") for (int i_ = 0; i_ < 8; ++i_) {                        \
        int pi_ = b_ + i_; if (pi_ > pend) pi_ = pend;                        \
        float4 x_ = W[i_];                                                    \
        x_.x += EPSQ; x_.y += EPSQ; x_.z += EPSQ; x_.w += EPSQ;               \
        *(float4*)&ringF[(((2*pi_)&63)<<7) + (lane<<2)] = x_; } } while(0)

#define B_LOAD(W, KC) do { const int b_ = 8*(KC);                             \
    _Pragma("unroll") for (int i_ = 0; i_ < 8; ++i_) {                        \
        int ii_ = b_ + i_; if (ii_ > pstart) ii_ = pstart;                    \
        W[i_] = rp4[(size_t)(pstart - ii_)*64 + lane]; } } while(0)
#define B_WRITE(W, KC) do { const int b_ = 8*(KC);                            \
    _Pragma("unroll") for (int i_ = 0; i_ < 8; ++i_) {                        \
        int ii_ = b_ + i_; if (ii_ > pstart) ii_ = pstart;                    \
        int jj_ = t0 - 2*(pstart - ii_) - hi_;                                \
        float4 x_ = W[i_];                                                    \
        x_.x += EPSQ; x_.y += EPSQ; x_.z += EPSQ; x_.w += EPSQ;               \
        *(float4*)&ringF[((jj_&63)<<7) + lo16_] = x_; } } while(0)

__global__ void __launch_bounds__(64, 1)
ctc_kernel(const float* __restrict__ y_pred,
           const int* __restrict__ labels,
           const int* __restrict__ feat_lens,
           const int* __restrict__ label_lens,
           float* __restrict__ ws)
{
    __shared__ int smem[SMEMN];
    float* ringF = (float*)smem;

    const int bid = blockIdx.x;
    const int b = bid >> 1;
    const int role = bid & 1;          // 0 = alpha, 1 = beta
    const int lane = threadIdx.x & 63;

    int f = feat_lens[b];
    f = (f + 1) >> 1; f = (f + 1) >> 1;
    const int Tbm1 = f - 1;
    const int m = f >> 1;

    const int* labrow = labels + b * LDIM;
    for (int i = lane; i < LDIM; i += 64) smem[LABSI + i] = labrow[i];
    __syncthreads();

    // per-lane tables: states s0..s0+7, s0 = 8*lane (even). Odd j=2u+1 are
    // labels kk = 4*lane+u; even j are blank (col 127).
    int cl[4]; float skl[4];
#pragma unroll
    for (int u = 0; u < 4; ++u) {
        int kk = 4*lane + u;
        int c = CDIM - 1; float sk = 0.f;
        if (kk < LDIM && (8*lane + 2*u + 1) < (2*LDIM + 1)) {
            c = smem[LABSI + kk];
            if (kk >= 1 && smem[LABSI + kk] != smem[LABSI + kk - 1]) sk = 1.f;
        }
        cl[u] = c; skl[u] = sk;
    }
    const float sk1 = skl[0], sk3 = skl[1], sk5 = skl[2], sk7 = skl[3];
    const int cl0 = cl[0], cl1 = cl[1], cl2 = cl[2], cl3 = cl[3];

    const float4* rp4 = (const float4*)(y_pred + (size_t)b * TDIM * CDIM);
    const int llen = label_lens[b];
    const int i1 = 2*llen - 1, i2 = 2*llen;
    const int s0 = lane * SPL;

    if (role == 0) {
        // ================= alpha (t = 0..m) =================
        const int pend = (m + 18) >> 1;
        float4 wA[8], wB[8];
        float a[SPL], ac[SPL];
        float qb[4], ql[4][4];
        int E = 0, Eac = 0; float fprev = 0.f;
#pragma unroll
        for (int j = 0; j < SPL; ++j) { a[j] = 0.f; ac[j] = 0.f; }
        qb[0] = 0.f; ql[0][0]=ql[0][1]=ql[0][2]=ql[0][3]=0.f;

        A_LOAD(wA, 0); A_LOAD(wB, 1); A_WRITE(wA, 0);
        asm volatile("s_waitcnt lgkmcnt(0)" ::: "memory");
#pragma unroll
        for (int r = 1; r <= 3; ++r) {
            qb[r]    = ringF[(r<<7) + 127];
            ql[r][0] = ringF[(r<<7) + cl0];
            ql[r][1] = ringF[(r<<7) + cl1];
            ql[r][2] = ringF[(r<<7) + cl2];
            ql[r][3] = ringF[(r<<7) + cl3];
        }
        { float v0b = ringF[127], v0l = ringF[cl0];
          if (lane == 0) { a[0] = v0b; a[1] = v0l; } }

        int t = 1, k = 0;
        while (t + 64 <= m) {
            A_LOAD(wA, k+2); A_WRITE(wB, k+1); A16(0)
            A_LOAD(wB, k+3); A_WRITE(wA, k+2); A16(16)
            A_LOAD(wA, k+4); A_WRITE(wB, k+3); A16(32)
            A_LOAD(wB, k+5); A_WRITE(wA, k+4); A16(48)
            t += 64; k += 4;
        }
        while (t <= m) {
            if (k & 1) { A_LOAD(wB, k+2); A_WRITE(wA, k+1); }
            else       { A_LOAD(wA, k+2); A_WRITE(wB, k+1); }
            RA AT4(0) RA AT4(4) RA AT4(8) RA AT4(12)
            t += 16; k += 1;
        }
        float* wsb = ws + (size_t)b * 2048;
#pragma unroll
        for (int j = 0; j < SPL; ++j) wsb[lane * SPL + j] = ac[j];
        ((int*)wsb)[512 + lane] = Eac;
    } else {
        // ================= beta (rows Tbm1 down to m+1) =================
        const int t0 = Tbm1;
        const int nb = t0 - m;
        const int scap = nb - 1;
        const int pstart = t0 >> 1;
        const int hi_ = lane >> 5;
        const int lo16_ = (lane & 31) << 2;
        float4 wA[8], wB[8];
        float bb[SPL], bc[SPL];
        float qb[4], ql[4][4];
        int E = 0, Ebc = 0; float fnext = 0.f;
#pragma unroll
        for (int j = 0; j < SPL; ++j) {
            int s = s0 + j;
            bb[j] = (s == i1 || s == i2) ? 1.f : 0.f;
            bc[j] = 0.f;
        }
        const float skb7 = (lane == 63) ? 0.f : __shfl_down(sk1, 1, 64);
        qb[3] = 0.f; ql[3][0]=ql[3][1]=ql[3][2]=ql[3][3]=0.f;

        B_LOAD(wA, 0); B_LOAD(wB, 1); B_WRITE(wA, 0);
        asm volatile("s_waitcnt lgkmcnt(0)" ::: "memory");
#pragma unroll
        for (int r = 0; r <= 2; ++r) {
            qb[r]    = ringF[(r<<7) + 127];
            ql[r][0] = ringF[(r<<7) + cl0];
            ql[r][1] = ringF[(r<<7) + cl1];
            ql[r][2] = ringF[(r<<7) + cl2];
            ql[r][3] = ringF[(r<<7) + cl3];
        }

        int s = 0, k = 0;
        while (s + 64 <= scap) {
            B_LOAD(wA, k+2); B_WRITE(wB, k+1); B16(0)
            B_LOAD(wB, k+3); B_WRITE(wA, k+2); B16(16)
            B_LOAD(wA, k+4); B_WRITE(wB, k+3); B16(32)
            B_LOAD(wB, k+5); B_WRITE(wA, k+4); B16(48)
            s += 64; k += 4;
        }
        while (s < nb) {
            if (k & 1) { B_LOAD(wB, k+2); B_WRITE(wA, k+1); }
            else       { B_LOAD(wA, k+2); B_WRITE(wB, k+1); }
            RB BT4(0) RB BT4(4) RB BT4(8) RB BT4(12)
            s += 16; k += 1;
        }
        float* wsb = ws + (size_t)b * 2048 + 1024;
#pragma unroll
        for (int j = 0; j < SPL; ++j) wsb[lane * SPL + j] = bc[j];
        ((int*)wsb)[512 + lane] = Ebc;
    }
}

__global__ void __launch_bounds__(64, 1)
ctc_combine(const float* __restrict__ ws, float* __restrict__ out)
{
    const int b = blockIdx.x;
    const int lane = threadIdx.x & 63;
    const float* wa = ws + (size_t)b * 2048;
    const float* wb = wa + 1024;
    const int Ea = ((const int*)wa)[512 + lane];
    const int Eb = ((const int*)wb)[512 + lane];
    float dot = 0.f;
#pragma unroll
    for (int j = 0; j < SPL; ++j)
        dot = fmaf(wa[lane * SPL + j], wb[lane * SPL + j], dot);
    float l2 = (dot > 0.f) ? (log2f(dot) + (float)(Ea + Eb)) : -1e30f;
    float M = l2;
#pragma unroll
    for (int d = 1; d < 64; d <<= 1) M = fmaxf(M, __shfl_xor(M, d, 64));
    float S = exp2f(l2 - M);
#pragma unroll
    for (int d = 1; d < 64; d <<= 1) S += __shfl_xor(S, d, 64);
    if (lane == 0) out[b] = -(M + log2f(S)) * 0.69314718055994530942f;
}

extern "C" void kernel_launch(void* const* d_in, const int* in_sizes, int n_in,
                              void* d_out, int out_size, void* d_ws, size_t ws_size,
                              hipStream_t stream) {
    (void)n_in; (void)out_size; (void)ws_size;
    const float* y_pred     = (const float*)d_in[0];
    const int*   labels     = (const int*)d_in[1];
    const int*   feat_lens  = (const int*)d_in[2];
    const int*   label_lens = (const int*)d_in[3];
    float* out = (float*)d_out;
    float* ws  = (float*)d_ws;
    const int B = in_sizes[2];  // 128
    ctc_kernel<<<B * 2, 64, 0, stream>>>(y_pred, labels, feat_lens, label_lens, ws);
    ctc_combine<<<B, 64, 0, stream>>>(ws, out);
}